// Round 8
// baseline (2749.524 us; speedup 1.0000x reference)
//
#include <hip/hip_runtime.h>

// Wave-per-board: one 64-lane wave handles one board start to finish.
// NO __syncthreads anywhere: per-wave LDS operations execute in issue order
// (hardware in-order DS pipe), so cross-lane LDS dataflow needs only
// __builtin_amdgcn_wave_barrier() compiler fences (idiom validated in R5-R7's
// do_FC). Decision math (H1, hidden, y, softmax) is f64 with the exact
// summation structure of R3/R7 (validated): equal count-triples give
// bit-identical scores -> np first-index tie-breaks reproduced by strict->
// comparisons in index order.
//
// Affected set of one fill = 9 row + 9 col + 4 off-row/off-col box = 22 slots
// (filled cell appears in row+col lists; skipped via score_l < 0).

__device__ __forceinline__ int affected_cell(int slot, int fr, int fc) {
    if (slot < 9)  return fr * 9 + slot;            // row cells
    if (slot < 18) return (slot - 9) * 9 + fc;      // col cells
    int r0 = (fr / 3) * 3, c0 = (fc / 3) * 3;       // box cells off-row/off-col
    int dr = fr - r0, dc = fc - c0;
    int rA = r0 + (dr == 0 ? 1 : 0), rB = r0 + (dr == 2 ? 1 : 2);
    int cA = c0 + (dc == 0 ? 1 : 0), cB = c0 + (dc == 2 ? 1 : 2);
    int k = slot - 18;
    return ((k < 2) ? rA : rB) * 9 + ((k & 1) ? cB : cA);
}

// F + C for one batch of up to 22 cells. init mode: c0>=0 -> cell = c0+slot;
// main mode: c0<0 -> cell = affected_cell(slot, fr, fc).
__device__ __forceinline__ void fc_pass(int c0, int fr, int fc, int l,
    const double* H1, double* pbuf, double* ybuf,
    double* score_l, int* pos_l, const double* W2Td, float* outp)
{
    // F: 110 (slot,q) units, 20-j partial dot each (R3-validated structure)
#pragma unroll
    for (int r = 0; r < 2; r++) {
        int u = r * 64 + l;
        if (u < 110) {
            int slot = u % 22, q = u / 22;
            int cell = (c0 >= 0) ? ((c0 + slot < 81) ? c0 + slot : -1)
                                 : affected_cell(slot, fr, fc);
            if (cell >= 0 && score_l[cell] >= 0.0) {
                int rr = cell / 9, cc = cell - 9 * rr;
                int bx = (rr / 3) * 3 + cc / 3;
                const double* Hr = H1 + rr * 102;
                const double* Hc = H1 + (9 + cc) * 102;
                const double* Hb = H1 + (18 + bx) * 102;
                double acc[9];
#pragma unroll
                for (int v = 0; v < 9; v++) acc[v] = 0.0;
                const int j0 = q * 20;
#pragma unroll
                for (int jj = 0; jj < 20; jj++) {
                    int j = j0 + jj;
                    double h = Hr[j] + Hc[j] + Hb[j];
                    h = h > 0.0 ? h : 0.0;
                    const double* w = W2Td + j * 9;
#pragma unroll
                    for (int v = 0; v < 9; v++) acc[v] = fma(h, w[v], acc[v]);
                }
                double* pb = pbuf + (slot * 5 + q) * 9;
#pragma unroll
                for (int v = 0; v < 9; v++) pb[v] = acc[v];
            }
        }
    }
    __builtin_amdgcn_wave_barrier();
    // C1: 198 (slot,v) units: y = sum_q partials (ascending q, R3 order)
    double yreg[4], ereg[4];
    int ucell[4], uslot[4], uv[4];
#pragma unroll
    for (int r = 0; r < 4; r++) {
        int u = r * 64 + l;
        int slot = 0, v = 0, cell = -1;
        if (u < 198) {
            slot = u % 22; v = u / 22;
            cell = (c0 >= 0) ? ((c0 + slot < 81) ? c0 + slot : -1)
                             : affected_cell(slot, fr, fc);
            if (cell >= 0 && score_l[cell] < 0.0) cell = -1;
        }
        double y = 0.0;
        if (cell >= 0) {
#pragma unroll
            for (int q = 0; q < 5; q++) y += pbuf[(slot * 5 + q) * 9 + v];
            ybuf[slot * 9 + v] = y;
        }
        yreg[r] = y; ucell[r] = cell; uslot[r] = slot; uv[r] = v;
    }
    __builtin_amdgcn_wave_barrier();
    // C2: m = max_v y (ascending fmax, R3 order), e = exp(y - m)
#pragma unroll
    for (int r = 0; r < 4; r++) {
        ereg[r] = 0.0;
        if (ucell[r] >= 0) {
            int slot = uslot[r];
            double m = ybuf[slot * 9 + 0];
#pragma unroll
            for (int v2 = 1; v2 < 9; v2++) m = fmax(m, ybuf[slot * 9 + v2]);
            ereg[r] = exp(yreg[r] - m);
        }
    }
    __builtin_amdgcn_wave_barrier();
    // write e into pbuf[0..197] (dead after C1: safe alias, in-order DS pipe)
#pragma unroll
    for (int r = 0; r < 4; r++)
        if (ucell[r] >= 0) pbuf[uslot[r] * 9 + uv[r]] = ereg[r];
    __builtin_amdgcn_wave_barrier();
    // C3: sum_e (ascending v, R3 order), probs out, score/pos cache
#pragma unroll
    for (int r = 0; r < 4; r++) {
        if (ucell[r] >= 0) {
            int slot = uslot[r], v = uv[r], cell = ucell[r];
            double ee[9], sum = 0.0;
#pragma unroll
            for (int v2 = 0; v2 < 9; v2++) { ee[v2] = pbuf[slot * 9 + v2]; sum += ee[v2]; }
            double inv = 1.0 / sum;
            outp[cell * 9 + v] = (float)(ereg[r] * inv);
            if (v == 0) {
                double best = -1.0; int bp = 0;
#pragma unroll
                for (int v2 = 0; v2 < 9; v2++) {
                    double pr = ee[v2] * inv;
                    if (pr > best) { best = pr; bp = v2; }  // strict > : first-index
                }
                score_l[cell] = best;
                pos_l[cell] = bp;
            }
        }
    }
    __builtin_amdgcn_wave_barrier();
}

__global__ __launch_bounds__(64) void sudoku_kernel(
    const float* __restrict__ x_in,
    const float* __restrict__ W1,
    const float* __restrict__ W2,
    float* __restrict__ out,
    int nb)
{
    const int b = blockIdx.x;
    const int l = threadIdx.x;

    // 40,680 B total -> 4 blocks/CU (4 x 40,960 = 160 KiB exactly)
    __shared__ double H1[27 * 102];    // stride 102: 16B-aligned rows
    __shared__ double pbuf[990];       // [slot][q][v]; [0..197] reused as ebuf
    __shared__ double W2Td[900];       // W2Td[j*9+v] = (double)W2[v*100+j]
    __shared__ double ybuf[198];
    __shared__ double score_l[81];     // -1 = filled
    __shared__ float  cnt[243];        // exact small ints
    __shared__ int    pos_l[81];

    const float* xb = x_in + (size_t)b * 729;
    float* outp = out + (size_t)b * 729;
    float* outx = out + (size_t)nb * 729 + (size_t)b * 729;

    // init: output copies + W2Td
#pragma unroll
    for (int r = 0; r < 12; r++) {
        int i = r * 64 + l;
        if (i < 729) { float v = xb[i]; outp[i] = v; outx[i] = v; }
    }
#pragma unroll
    for (int r = 0; r < 15; r++) {
        int i = r * 64 + l;
        if (i < 900) { int v = i / 100, j = i - 100 * v; W2Td[j * 9 + v] = (double)W2[i]; }
    }
    // empty flags (0.0 sentinel) + pos init
#pragma unroll
    for (int r = 0; r < 2; r++) {
        int u = r * 64 + l;
        if (u < 81) {
            float s = 0.f;
#pragma unroll
            for (int v = 0; v < 9; v++) s += xb[u * 9 + v];
            score_l[u] = (s == 0.f) ? 0.0 : -1.0;
            pos_l[u] = 0;
        }
    }
    // initial counts (sums of 0/1 -> exact in f32)
#pragma unroll
    for (int r = 0; r < 4; r++) {
        int o = r * 64 + l;
        if (o < 243) {
            int g = o / 9, v = o - 9 * g;
            float s = 0.f;
            if (g < 9) {
                int base = g * 9;
#pragma unroll
                for (int k = 0; k < 9; k++) s += xb[(base + k) * 9 + v];
            } else if (g < 18) {
                int c = g - 9;
#pragma unroll
                for (int k = 0; k < 9; k++) s += xb[(c + 9 * k) * 9 + v];
            } else {
                int bx = g - 18;
                int base = (bx / 3) * 27 + (bx % 3) * 3;
#pragma unroll
                for (int k = 0; k < 9; k++) s += xb[(base + (k / 3) * 9 + (k % 3)) * 9 + v];
            }
            cnt[o] = s;
        }
    }
    __builtin_amdgcn_wave_barrier();
    // full H1 init (canonical v-order fma, same function as main-loop H)
    for (int r = 0; r < 43; r++) {
        int o = r * 64 + l;
        if (o < 2700) {
            int g = o / 100, j = o - 100 * g;
            int type = (g >= 18) ? 2 : (g >= 9 ? 1 : 0);
            const float* w = W1 + j * 27 + type * 9;
            double s = 0.0;
#pragma unroll
            for (int v = 0; v < 9; v++) s = fma((double)w[v], (double)cnt[g * 9 + v], s);
            H1[g * 102 + j] = s;
        }
    }
    // preload this lane's main-loop W1 slice into registers (fixed (gi,j) per k)
    float w1r[5][9];
#pragma unroll
    for (int k = 0; k < 5; k++) {
        int o = k * 64 + l; if (o >= 300) o = 0;
        int gi = o / 100, j = o - 100 * gi;
#pragma unroll
        for (int v = 0; v < 9; v++) w1r[k][v] = W1[j * 27 + gi * 9 + v];
    }
    __builtin_amdgcn_wave_barrier();

    // initial probs/scores for all empty cells (4 batches of 22)
    fc_pass(0,  0, 0, l, H1, pbuf, ybuf, score_l, pos_l, W2Td, outp);
    fc_pass(22, 0, 0, l, H1, pbuf, ybuf, score_l, pos_l, W2Td, outp);
    fc_pass(44, 0, 0, l, H1, pbuf, ybuf, score_l, pos_l, W2Td, outp);
    fc_pass(66, 0, 0, l, H1, pbuf, ybuf, score_l, pos_l, W2Td, outp);

    int ne = __popcll(__ballot(score_l[l] >= 0.0));
    ne += __popcll(__ballot(l < 17 && score_l[64 + l] >= 0.0));

    // main loop: one fill per iteration, single wave, no block barriers
    for (int step = 0; step < ne; ++step) {
        // ARG: butterfly argmax over 81 scores, first-index tie-break
        double s = score_l[l]; int idx = l;
        if (l < 17) {
            double s2 = score_l[64 + l];
            if (s2 > s) { s = s2; idx = 64 + l; }  // tie keeps lower idx
        }
#pragma unroll
        for (int off = 1; off < 64; off <<= 1) {
            double s2 = __shfl_xor(s, off);
            int    i2 = __shfl_xor(idx, off);
            if (s2 > s || (s2 == s && i2 < idx)) { s = s2; idx = i2; }
        }
        const int fcell = idx;
        const int bv = pos_l[fcell];
        const int fr = fcell / 9, fc = fcell - 9 * fr;
        const int fbx = (fr / 3) * 3 + fc / 3;
        if (l == 0) {
            score_l[fcell] = -1.0;
            cnt[fr * 9 + bv] += 1.f;
            cnt[(9 + fc) * 9 + bv] += 1.f;
            cnt[(18 + fbx) * 9 + bv] += 1.f;
            outx[fcell * 9 + bv] = 1.0f;   // fill recorded directly in global x
        }
        __builtin_amdgcn_wave_barrier();
        // H: fresh H1 for the 3 dirty groups (register W1, canonical v-order)
#pragma unroll
        for (int k = 0; k < 5; k++) {
            int o = k * 64 + l;
            if (o < 300) {
                int gi = o / 100, j = o - 100 * gi;
                int g = (gi == 0) ? fr : (gi == 1) ? (9 + fc) : (18 + fbx);
                double h = 0.0;
#pragma unroll
                for (int v = 0; v < 9; v++)
                    h = fma((double)w1r[k][v], (double)cnt[g * 9 + v], h);
                H1[g * 102 + j] = h;
            }
        }
        __builtin_amdgcn_wave_barrier();
        // F + C for the 22 affected cells
        fc_pass(-1, fr, fc, l, H1, pbuf, ybuf, score_l, pos_l, W2Td, outp);
    }
}

extern "C" void kernel_launch(void* const* d_in, const int* in_sizes, int n_in,
                              void* d_out, int out_size, void* d_ws, size_t ws_size,
                              hipStream_t stream) {
    const float* x  = (const float*)d_in[0];
    const float* W1 = (const float*)d_in[1];
    const float* W2 = (const float*)d_in[2];
    int nb = in_sizes[0] / 729;
    (void)n_in; (void)out_size; (void)d_ws; (void)ws_size;
    sudoku_kernel<<<nb, 64, 0, stream>>>(x, W1, W2, (float*)d_out, nb);
}

// Round 10
// 2668.741 us; speedup vs baseline: 1.0303x; 1.0303x over previous
//
#include <hip/hip_runtime.h>

#define TPB 256

// Block-per-board, ONE __syncthreads per step, race-free by construction:
// - scores double-buffered: ARG reads scur (read-only all step); C writes
//   snext for {affected, !=fcell, scur>=0}; copier (t<81) writes snext for the
//   complement (+ snext[fcell] = -1). Writer sets disjoint; all cross-wave
//   read/write pairs barrier-separated. No timing assumptions.
// - every wave: redundant shfl-butterfly argmax, private u8 cnt copy,
//   redundant recompute of the 3 dirty H1 rows (identical bits -> concurrent
//   same-address LDS writes benign; own reads ordered by in-order DS pipe +
//   wave_barrier compiler fences).
// - slot's 9 v-lanes contiguous in one wave -> softmax via __shfl in ascending
//   v order (bit-identical to the validated LDS version).
// Decision math (H1, hidden, y, softmax) is f64 with the canonical summation
// structure validated R2-R8: equal count-triples give bit-identical scores ->
// np first-index tie-breaks via strict-> comparisons in index order.
//
// Affected set of one fill = 9 row + 9 col + 4 off-row/off-col box = 22 slots.

__device__ __forceinline__ int affected_cell(int slot, int fr, int fc) {
    if (slot < 9)  return fr * 9 + slot;            // row cells
    if (slot < 18) return (slot - 9) * 9 + fc;      // col cells
    int r0 = (fr / 3) * 3, c0 = (fc / 3) * 3;       // box cells off-row/off-col
    int dr = fr - r0, dc = fc - c0;
    int rA = r0 + (dr == 0 ? 1 : 0), rB = r0 + (dr == 2 ? 1 : 2);
    int cA = c0 + (dc == 0 ? 1 : 0), cB = c0 + (dc == 2 ? 1 : 2);
    int k = slot - 18;
    return ((k < 2) ? rA : rB) * 9 + ((k & 1) ? cB : cA);
}

// Wave-local F (30 lanes: 6 slots x 5 j-chunks of 20) then C (54 lanes:
// 6 slots x 9 v). init mode: c0>=0 -> cell = c0+slot; main: affected_cell.
__device__ __forceinline__ void fc_pass(int c0, int fcell, int fr, int fcol,
    int l, int slotBase,
    const double* __restrict__ H1, const double* __restrict__ W2Td,
    double* __restrict__ pbuf, const double* __restrict__ scur,
    double* __restrict__ snext, int* __restrict__ pos_l,
    float* __restrict__ outp)
{
    // ---- F: partial y over 20-j chunk (R3/R8-validated structure) ----
    if (l < 30) {
        int ls = l / 5, q = l - 5 * ls;
        int slot = slotBase + ls;
        if (slot < 22) {
            int cell = (c0 >= 0) ? (c0 + slot) : affected_cell(slot, fr, fcol);
            if (cell < 81 && cell != fcell && scur[cell] >= 0.0) {
                int rr = cell / 9, cc = cell - 9 * rr;
                int bx = (rr / 3) * 3 + cc / 3;
                const double* Hr = H1 + rr * 101;
                const double* Hc = H1 + (9 + cc) * 101;
                const double* Hb = H1 + (18 + bx) * 101;
                double acc[9];
#pragma unroll
                for (int v = 0; v < 9; v++) acc[v] = 0.0;
                const int j0 = q * 20;
#pragma unroll 4
                for (int jj = 0; jj < 20; jj++) {
                    int j = j0 + jj;
                    double h = Hr[j] + Hc[j] + Hb[j];
                    h = h > 0.0 ? h : 0.0;
                    const double* w = W2Td + j * 9;
#pragma unroll
                    for (int v = 0; v < 9; v++) acc[v] = fma(h, w[v], acc[v]);
                }
                double* pb = pbuf + (slot * 5 + q) * 9;
#pragma unroll
                for (int v = 0; v < 9; v++) pb[v] = acc[v];
            }
        }
    }
    __builtin_amdgcn_wave_barrier();
    // ---- C: combine + shuffle softmax (ascending-order, bit-identical) ----
    if (l < 54) {
        int ls = l / 9, v = l - 9 * ls;
        int slot = slotBase + ls;
        if (slot < 22) {
            int cell = (c0 >= 0) ? (c0 + slot) : affected_cell(slot, fr, fcol);
            if (cell < 81 && cell != fcell && scur[cell] >= 0.0) {
                double y = 0.0;
#pragma unroll
                for (int q2 = 0; q2 < 5; q2++) y += pbuf[(slot * 5 + q2) * 9 + v];
                const int base = ls * 9;               // wave-lane base of slot
                double m = __shfl(y, base);
#pragma unroll
                for (int k = 1; k < 9; k++) m = fmax(m, __shfl(y, base + k));
                double e = exp(y - m);
                double sum = 0.0;
#pragma unroll
                for (int k = 0; k < 9; k++) sum += __shfl(e, base + k);
                double inv = 1.0 / sum;
                double pr = e * inv;
                outp[cell * 9 + v] = (float)pr;
                double best = -1.0; int bp = 0;
#pragma unroll
                for (int k = 0; k < 9; k++) {
                    double pk = __shfl(pr, base + k);
                    if (pk > best) { best = pk; bp = k; }  // strict > : first-index
                }
                if (v == 0) { snext[cell] = best; pos_l[cell] = bp; }
            }
        }
    }
    __builtin_amdgcn_wave_barrier();
}

__global__ __launch_bounds__(TPB, 4) void sudoku_kernel(
    const float* __restrict__ x_in,
    const float* __restrict__ W1,
    const float* __restrict__ W2,
    float* __restrict__ out,
    int nb)
{
    const int b = blockIdx.x;
    const int t = threadIdx.x;
    const int W = t >> 6, l = t & 63;
    const int slotBase = W * 6;

    // 39,532 B -> 4 blocks/CU (16 waves/CU)
    __shared__ double H1[27 * 101];          // 21,816 B (odd stride: no conflicts)
    __shared__ double W2Td[100 * 9];         //  7,200 B
    __shared__ double pbuf[22 * 5 * 9];      //  7,920 B [slot][q][v]
    __shared__ double sb0[81], sb1[81];      //  1,296 B score double-buffer
    __shared__ int    pos_l[81];             //    324 B
    __shared__ unsigned char cntw[4 * 244];  //    976 B per-wave cnt copies

    const float* xb = x_in + (size_t)b * 729;
    float* outp = out + (size_t)b * 729;
    float* outx = out + (size_t)nb * 729 + (size_t)b * 729;

    // init: output copies + W2Td (block-split)
    for (int i = t; i < 729; i += TPB) { float v = xb[i]; outp[i] = v; outx[i] = v; }
    for (int i = t; i < 900; i += TPB) {
        int v = i / 100, j = i - 100 * v;
        W2Td[j * 9 + v] = (double)W2[i];
    }
    // empty flags (0.0 sentinel) + pos init (waves 0-1; visible after barrier)
    if (t < 81) {
        float s = 0.f;
#pragma unroll
        for (int v = 0; v < 9; v++) s += xb[t * 9 + v];
        sb0[t] = (s == 0.f) ? 0.0 : -1.0;
        pos_l[t] = 0;
    }
    // per-wave cnt copy (exact small ints)
    unsigned char* cw = cntw + W * 244;
#pragma unroll
    for (int r = 0; r < 4; r++) {
        int o = r * 64 + l;
        if (o < 243) {
            int g = o / 9, v = o - 9 * g;
            float s = 0.f;
            if (g < 9) {
                int base = g * 9;
#pragma unroll
                for (int k = 0; k < 9; k++) s += xb[(base + k) * 9 + v];
            } else if (g < 18) {
                int c = g - 9;
#pragma unroll
                for (int k = 0; k < 9; k++) s += xb[(c + 9 * k) * 9 + v];
            } else {
                int bx = g - 18;
                int base = (bx / 3) * 27 + (bx % 3) * 3;
#pragma unroll
                for (int k = 0; k < 9; k++) s += xb[(base + (k / 3) * 9 + (k % 3)) * 9 + v];
            }
            cw[o] = (unsigned char)(int)s;
        }
    }
    __builtin_amdgcn_wave_barrier();
    // full H1 init, redundant per wave (identical bits; own reads see own writes)
    for (int r = 0; r < 43; r++) {
        int o = r * 64 + l;
        if (o < 2700) {
            int g = o / 100, j = o - 100 * g;
            int type = (g >= 18) ? 2 : (g >= 9 ? 1 : 0);
            const float* w = W1 + j * 27 + type * 9;
            const unsigned char* cg = cw + g * 9;
            double s = 0.0;
#pragma unroll
            for (int v = 0; v < 9; v++) s = fma((double)w[v], (double)cg[v], s);
            H1[g * 101 + j] = s;
        }
    }
    __syncthreads();   // flags + W2Td visible to all waves

    // initial probs/scores for all empty cells (own slots, 4 passes; snext=sb0:
    // per-wave-disjoint cells, each processed once -> no conflicting writers)
    for (int p = 0; p < 4; p++)
        fc_pass(p * 22, -1, 0, 0, l, slotBase, H1, W2Td, pbuf, sb0, sb0, pos_l, outp);
    __syncthreads();   // all scores visible

    int ne = __popcll(__ballot(sb0[l] >= 0.0));
    ne += __popcll(__ballot((l < 17) && (sb0[64 + l] >= 0.0)));

    double* scur = sb0;
    double* snext = sb1;

    // main loop: ONE block barrier per step
    for (int step = 0; step < ne; ++step) {
        // ARG: redundant per-wave butterfly argmax over scur (read-only all step)
        double s = scur[l]; int idx = l;
        if (l < 17) {
            double s2 = scur[64 + l];
            if (s2 > s) { s = s2; idx = 64 + l; }   // tie keeps lower idx
        }
#pragma unroll
        for (int off = 1; off < 64; off <<= 1) {
            double s2 = __shfl_xor(s, off);
            int    i2 = __shfl_xor(idx, off);
            if (s2 > s || (s2 == s && i2 < idx)) { s = s2; idx = i2; }
        }
        const int fcell = idx;
        const int bv = pos_l[fcell];
        const int frow = fcell / 9, fcol = fcell - 9 * frow;
        const int fbx = (frow / 3) * 3 + fcol / 3;

        if (t == 0) outx[fcell * 9 + bv] = 1.0f;   // record fill in global x
        if (l == 0) {                              // each wave: own cnt copy
            cw[frow * 9 + bv] += 1;
            cw[(9 + fcol) * 9 + bv] += 1;
            cw[(18 + fbx) * 9 + bv] += 1;
        }
        __builtin_amdgcn_wave_barrier();

        // H: 3 dirty rows, redundant per wave (canonical v-order, same bits)
#pragma unroll
        for (int k = 0; k < 5; k++) {
            int o = k * 64 + l;
            if (o < 300) {
                int gi = o / 100, j = o - 100 * gi;
                int g = (gi == 0) ? frow : (gi == 1) ? (9 + fcol) : (18 + fbx);
                const float* w = W1 + j * 27 + gi * 9;
                const unsigned char* cg = cw + g * 9;
                double h = 0.0;
#pragma unroll
                for (int v = 0; v < 9; v++) h = fma((double)w[v], (double)cg[v], h);
                H1[g * 101 + j] = h;
            }
        }
        __builtin_amdgcn_wave_barrier();

        // F + C for the 22 affected cells (C writes snext for {aff,!=fcell,scur>=0})
        fc_pass(-1, fcell, frow, fcol, l, slotBase, H1, W2Td, pbuf, scur, snext, pos_l, outp);

        // copier: carry the complement scur -> snext; fcell gets -1
        if (t < 81) {
            int cr = t / 9, cc = t - 9 * cr;
            bool aff = (cr == frow) || (cc == fcol) ||
                       ((cr / 3) == (frow / 3) && (cc / 3) == (fcol / 3));
            double sc = scur[t];
            if (t == fcell) snext[t] = -1.0;
            else if (!(aff && sc >= 0.0)) snext[t] = sc;
        }
        __syncthreads();
        double* tmp = scur; scur = snext; snext = tmp;
    }
}

extern "C" void kernel_launch(void* const* d_in, const int* in_sizes, int n_in,
                              void* d_out, int out_size, void* d_ws, size_t ws_size,
                              hipStream_t stream) {
    const float* x  = (const float*)d_in[0];
    const float* W1 = (const float*)d_in[1];
    const float* W2 = (const float*)d_in[2];
    int nb = in_sizes[0] / 729;
    (void)n_in; (void)out_size; (void)d_ws; (void)ws_size;
    sudoku_kernel<<<nb, TPB, 0, stream>>>(x, W1, W2, (float*)d_out, nb);
}